// Round 1
// baseline (4413.576 us; speedup 1.0000x reference)
//
#include <hip/hip_runtime.h>

// Differentiable SVM (multiclass hinge, 15 GD steps) on MI355X.
// Round 1: correctness-first fp32 VALU GEMMs.
//
// Shapes (fixed by reference setup):
//   S (support): [4096, 2048] f32,  labels: [4096] i32
//   Q (query):   [16384, 2048] f32, n_classes = 128
//   out:         [16384, 128] f32
//
// W stored transposed: WT[class][k], stride WSTRIDE, bias at col 2048.

#define NS 4096
#define DIM 2048
#define NQ 16384
#define NC 128
#define WSTRIDE 2052              // 2049 padded to multiple of 4 floats
#define LRATE 0.01f
#define SHRINK (1.0f - 0.01f * 1.0f)   // 1 - LR*C
#define GINV (1.0f / (4096.0f * 128.0f))
#define MAX_ITER 15

__device__ __forceinline__ void fma4(float* acc, const float4 b, const float a) {
    acc[0] = fmaf(a, b.x, acc[0]);
    acc[1] = fmaf(a, b.y, acc[1]);
    acc[2] = fmaf(a, b.z, acc[2]);
    acc[3] = fmaf(a, b.w, acc[3]);
}

__global__ __launch_bounds__(256) void k_zero(float* __restrict__ p, int n) {
    int i = blockIdx.x * 256 + threadIdx.x;
    if (i < n) p[i] = 0.0f;
}

// ---------------------------------------------------------------------------
// K1: scores = S @ WT^T + bias, then hinge gradient G (fused; N=128 in-block).
// Block: 256 threads, tile 32 rows x 128 classes. Grid: 128 blocks.
// ---------------------------------------------------------------------------
__global__ __launch_bounds__(256) void k_scores_grad(
    const float* __restrict__ S, const int* __restrict__ labels,
    const float* __restrict__ WT, float* __restrict__ G)
{
    __shared__ float sA[32][36];     // S tile, [row][k]
    __shared__ float sW[32][132];    // WT tile TRANSPOSED in LDS: [k][class]
    __shared__ float sc[32][128];    // scores tile
    __shared__ float sBias[128];
    __shared__ int   sLab[32];
    __shared__ int   sCnt[32][33];
    __shared__ int   sRowCnt[32];

    const int tid = threadIdx.x;
    const int i0 = blockIdx.x * 32;
    const int tx = tid & 31;         // class group: cols tx*4..tx*4+3
    const int ty = tid >> 5;         // row group: rows ty*4..ty*4+3

    if (tid < 128) sBias[tid] = WT[(size_t)tid * WSTRIDE + 2048];
    if (tid < 32)  sLab[tid] = labels[i0 + tid];

    float acc[4][4] = {};

    const int lr = tid >> 3;              // 0..31
    const int lc = (tid & 7) << 2;        // 0,4,...,28

    for (int k0 = 0; k0 < DIM; k0 += 32) {
        // stage S tile [32][32], coalesced float4
        *reinterpret_cast<float4*>(&sA[lr][lc]) =
            *reinterpret_cast<const float4*>(&S[(size_t)(i0 + lr) * DIM + k0 + lc]);
        // stage WT tile transposed: sW[k][class] so inner reads are conflict-free
        #pragma unroll
        for (int rr = 0; rr < 4; ++rr) {
            const int wrow = lr + rr * 32;   // class 0..127
            const float4 v = *reinterpret_cast<const float4*>(
                &WT[(size_t)wrow * WSTRIDE + k0 + lc]);
            sW[lc + 0][wrow] = v.x;
            sW[lc + 1][wrow] = v.y;
            sW[lc + 2][wrow] = v.z;
            sW[lc + 3][wrow] = v.w;
        }
        __syncthreads();
        #pragma unroll
        for (int kk = 0; kk < 32; kk += 4) {
            const float4 b0 = *reinterpret_cast<const float4*>(&sW[kk + 0][tx << 2]);
            const float4 b1 = *reinterpret_cast<const float4*>(&sW[kk + 1][tx << 2]);
            const float4 b2 = *reinterpret_cast<const float4*>(&sW[kk + 2][tx << 2]);
            const float4 b3 = *reinterpret_cast<const float4*>(&sW[kk + 3][tx << 2]);
            #pragma unroll
            for (int r = 0; r < 4; ++r) {
                const float4 a = *reinterpret_cast<const float4*>(&sA[(ty << 2) + r][kk]);
                fma4(acc[r], b0, a.x);
                fma4(acc[r], b1, a.y);
                fma4(acc[r], b2, a.z);
                fma4(acc[r], b3, a.w);
            }
        }
        __syncthreads();
    }

    // scores (with bias) -> LDS
    const float4 bias4 = *reinterpret_cast<const float4*>(&sBias[tx << 2]);
    #pragma unroll
    for (int r = 0; r < 4; ++r) {
        float4 v;
        v.x = acc[r][0] + bias4.x;
        v.y = acc[r][1] + bias4.y;
        v.z = acc[r][2] + bias4.z;
        v.w = acc[r][3] + bias4.w;
        *reinterpret_cast<float4*>(&sc[(ty << 2) + r][tx << 2]) = v;
    }
    __syncthreads();

    // per-row indicator counts
    #pragma unroll
    for (int r = 0; r < 4; ++r) {
        const int row = (ty << 2) + r;
        const int l = sLab[row];
        const float scorr = sc[row][l];
        int cnt = 0;
        #pragma unroll
        for (int c = 0; c < 4; ++c) {
            const int col = (tx << 2) + c;
            const float m = sc[row][col] - scorr + 1.0f;
            cnt += (col != l && m > 0.0f) ? 1 : 0;
        }
        sCnt[row][tx] = cnt;
    }
    __syncthreads();
    if (tid < 32) {
        int s = 0;
        #pragma unroll
        for (int t = 0; t < 32; ++t) s += sCnt[tid][t];
        sRowCnt[tid] = s;
    }
    __syncthreads();

    // write G row-major [4096][128]
    #pragma unroll
    for (int r = 0; r < 4; ++r) {
        const int row = (ty << 2) + r;
        const int l = sLab[row];
        const float scorr = sc[row][l];
        const float gl = -(float)sRowCnt[row] * GINV;
        const int colbase = tx << 2;
        float gv[4];
        #pragma unroll
        for (int c = 0; c < 4; ++c) {
            const int col = colbase + c;
            const float m = sc[row][col] - scorr + 1.0f;
            gv[c] = (col == l) ? gl : ((m > 0.0f) ? GINV : 0.0f);
        }
        float4 g;
        g.x = gv[0]; g.y = gv[1]; g.z = gv[2]; g.w = gv[3];
        *reinterpret_cast<float4*>(&G[(size_t)(i0 + row) * NC + colbase]) = g;
    }
}

// ---------------------------------------------------------------------------
// K2: dWT[j][k] = sum_i G[i][j] * S[i][k]; WT = WT*SHRINK - LR*dWT.
// Bias row handled by blockIdx.x==0 blocks (colsum of G).
// Block: 256 threads, tile 16 classes x 128 k. Grid: (16 k-tiles, 8 j-tiles).
// ---------------------------------------------------------------------------
__global__ __launch_bounds__(256) void k_update(
    const float* __restrict__ S, const float* __restrict__ G,
    float* __restrict__ WT)
{
    __shared__ float sG[16][36];    // G staged TRANSPOSED: [j][i]
    __shared__ float sS[32][132];   // S tile [i][k]
    __shared__ float sRed[16][17];

    const int tid = threadIdx.x;
    const int k0 = blockIdx.x * 128;
    const int j0 = blockIdx.y * 16;
    const int tx = tid & 31;          // k group: k = tx*4..+3
    const int ty = tid >> 5;          // j group: j = ty*2, ty*2+1

    float acc[2][4] = {};
    float bacc = 0.0f;
    const int gj = tid & 15;
    const int gii = tid >> 4;         // 0..15

    const int sr = tid >> 5;          // 0..7
    const int sc4 = (tid & 31) << 2;

    for (int ii0 = 0; ii0 < NS; ii0 += 32) {
        sG[gj][gii]      = G[(size_t)(ii0 + gii) * NC + j0 + gj];
        sG[gj][gii + 16] = G[(size_t)(ii0 + gii + 16) * NC + j0 + gj];
        #pragma unroll
        for (int rr = 0; rr < 4; ++rr) {
            *reinterpret_cast<float4*>(&sS[sr + rr * 8][sc4]) =
                *reinterpret_cast<const float4*>(
                    &S[(size_t)(ii0 + sr + rr * 8) * DIM + k0 + sc4]);
        }
        __syncthreads();
        if (blockIdx.x == 0) {  // bias colsum accumulation (uniform branch)
            bacc += sG[gj][gii] + sG[gj][gii + 16];
        }
        #pragma unroll
        for (int ii = 0; ii < 32; ii += 4) {
            const float4 b0 = *reinterpret_cast<const float4*>(&sS[ii + 0][tx << 2]);
            const float4 b1 = *reinterpret_cast<const float4*>(&sS[ii + 1][tx << 2]);
            const float4 b2 = *reinterpret_cast<const float4*>(&sS[ii + 2][tx << 2]);
            const float4 b3 = *reinterpret_cast<const float4*>(&sS[ii + 3][tx << 2]);
            #pragma unroll
            for (int jj = 0; jj < 2; ++jj) {
                const float4 a = *reinterpret_cast<const float4*>(&sG[(ty << 1) + jj][ii]);
                fma4(acc[jj], b0, a.x);
                fma4(acc[jj], b1, a.y);
                fma4(acc[jj], b2, a.z);
                fma4(acc[jj], b3, a.w);
            }
        }
        __syncthreads();
    }

    #pragma unroll
    for (int jj = 0; jj < 2; ++jj) {
        const int j = j0 + (ty << 1) + jj;
        float* wp = &WT[(size_t)j * WSTRIDE + k0 + (tx << 2)];
        float4 w = *reinterpret_cast<const float4*>(wp);
        w.x = w.x * SHRINK - LRATE * acc[jj][0];
        w.y = w.y * SHRINK - LRATE * acc[jj][1];
        w.z = w.z * SHRINK - LRATE * acc[jj][2];
        w.w = w.w * SHRINK - LRATE * acc[jj][3];
        *reinterpret_cast<float4*>(wp) = w;
    }

    if (blockIdx.x == 0) {
        sRed[gii][gj] = bacc;
        __syncthreads();
        if (tid < 16) {
            float s = 0.0f;
            #pragma unroll
            for (int t = 0; t < 16; ++t) s += sRed[t][tid];
            WT[(size_t)(j0 + tid) * WSTRIDE + 2048] -= LRATE * s;
        }
    }
}

// ---------------------------------------------------------------------------
// K3: out = Q @ WT^T + bias.  Tile 32 rows x 128 classes. Grid: 512 blocks.
// ---------------------------------------------------------------------------
__global__ __launch_bounds__(256) void k_query(
    const float* __restrict__ Q, const float* __restrict__ WT,
    float* __restrict__ out)
{
    __shared__ float sA[32][36];
    __shared__ float sW[32][132];
    __shared__ float sBias[128];

    const int tid = threadIdx.x;
    const int i0 = blockIdx.x * 32;
    const int tx = tid & 31;
    const int ty = tid >> 5;

    if (tid < 128) sBias[tid] = WT[(size_t)tid * WSTRIDE + 2048];

    float acc[4][4] = {};
    const int lr = tid >> 3;
    const int lc = (tid & 7) << 2;

    for (int k0 = 0; k0 < DIM; k0 += 32) {
        *reinterpret_cast<float4*>(&sA[lr][lc]) =
            *reinterpret_cast<const float4*>(&Q[(size_t)(i0 + lr) * DIM + k0 + lc]);
        #pragma unroll
        for (int rr = 0; rr < 4; ++rr) {
            const int wrow = lr + rr * 32;
            const float4 v = *reinterpret_cast<const float4*>(
                &WT[(size_t)wrow * WSTRIDE + k0 + lc]);
            sW[lc + 0][wrow] = v.x;
            sW[lc + 1][wrow] = v.y;
            sW[lc + 2][wrow] = v.z;
            sW[lc + 3][wrow] = v.w;
        }
        __syncthreads();
        #pragma unroll
        for (int kk = 0; kk < 32; kk += 4) {
            const float4 b0 = *reinterpret_cast<const float4*>(&sW[kk + 0][tx << 2]);
            const float4 b1 = *reinterpret_cast<const float4*>(&sW[kk + 1][tx << 2]);
            const float4 b2 = *reinterpret_cast<const float4*>(&sW[kk + 2][tx << 2]);
            const float4 b3 = *reinterpret_cast<const float4*>(&sW[kk + 3][tx << 2]);
            #pragma unroll
            for (int r = 0; r < 4; ++r) {
                const float4 a = *reinterpret_cast<const float4*>(&sA[(ty << 2) + r][kk]);
                fma4(acc[r], b0, a.x);
                fma4(acc[r], b1, a.y);
                fma4(acc[r], b2, a.z);
                fma4(acc[r], b3, a.w);
            }
        }
        __syncthreads();
    }

    const float4 bias4 = *reinterpret_cast<const float4*>(&sBias[tx << 2]);
    #pragma unroll
    for (int r = 0; r < 4; ++r) {
        float4 v;
        v.x = acc[r][0] + bias4.x;
        v.y = acc[r][1] + bias4.y;
        v.z = acc[r][2] + bias4.z;
        v.w = acc[r][3] + bias4.w;
        *reinterpret_cast<float4*>(
            &out[(size_t)(i0 + (ty << 2) + r) * NC + (tx << 2)]) = v;
    }
}

extern "C" void kernel_launch(void* const* d_in, const int* in_sizes, int n_in,
                              void* d_out, int out_size, void* d_ws, size_t ws_size,
                              hipStream_t stream)
{
    const float* S      = (const float*)d_in[0];
    const int*   labels = (const int*)d_in[1];
    const float* Q      = (const float*)d_in[2];
    float* out = (float*)d_out;

    // workspace layout: WT [128][WSTRIDE] f32, then G [4096][128] f32 (~3.1 MB)
    float* WT = (float*)d_ws;
    float* G  = WT + (size_t)NC * WSTRIDE;

    const int wtN = NC * WSTRIDE;
    k_zero<<<dim3((wtN + 255) / 256), dim3(256), 0, stream>>>(WT, wtN);

    for (int it = 0; it < MAX_ITER; ++it) {
        k_scores_grad<<<dim3(NS / 32), dim3(256), 0, stream>>>(S, labels, WT, G);
        k_update<<<dim3(16, 8), dim3(256), 0, stream>>>(S, G, WT);
    }
    k_query<<<dim3(NQ / 32), dim3(256), 0, stream>>>(Q, WT, out);
}

// Round 2
// 1945.835 us; speedup vs baseline: 2.2682x; 2.2682x over previous
//
#include <hip/hip_runtime.h>

// Differentiable SVM (multiclass hinge, 15 GD steps) on MI355X — Round 2.
// bf16 MFMA everywhere (16x16x32), fragment-packed operand layouts so all
// GEMM main loops are LDS-free / barrier-free register streams.
//
// Shapes: S[4096][2048] f32, labels[4096] i32, Q[16384][2048] f32,
//         out[16384][128] f32. W kept as WT[class][k] fp32 master + bias fp32.
//
// Fragment layout (v_mfma_f32_16x16x32_bf16), lane l, g=l>>4, q=l&15:
//   A: A[row=q][k=8g+e]  B: B[col=q][k=8g+e]  D: D[row=4g+r][col=q]
// Pack layouts ([tile][lane][8] ushort, 16B per lane, contiguous 1KB tiles):
//   SpackA/QpackA: tile(rt=row>>4, kt=k>>5): idx=((rt*64+kt)*64 + 16*((k&31)>>3)+(row&15))*8 + (k&7)
//   SpackB:        tile(kt2=k>>4, it=i>>5):  idx=((kt2*128+it)*64 + 16*((i&31)>>3)+(k&15))*8 + (i&7)
//   WTpack:        tile(kt=k>>5, jt=j>>4):   idx=((kt*8+jt)*64   + 16*((k&31)>>3)+(j&15))*8 + (k&7)
//   Gpack:         tile(jt=j>>4, it=i>>5):   idx=((jt*128+it)*64 + 16*((i&31)>>3)+(j&15))*8 + (i&7)

#define NS 4096
#define DIM 2048
#define NQ 16384
#define NC 128
#define LRATE 0.01f
#define SHRINK (1.0f - 0.01f * 1.0f)
#define GINVF (1.0f / (4096.0f * 128.0f))   // 2^-19, exact in bf16
#define MAX_ITER 15

typedef __attribute__((ext_vector_type(8))) short short8v;
typedef __attribute__((ext_vector_type(8))) unsigned short ushort8v;
typedef __attribute__((ext_vector_type(4))) float f32x4;

__device__ __forceinline__ unsigned short f2bf(float f) {     // RNE
    unsigned int u = __float_as_uint(f);
    u += 0x7fffu + ((u >> 16) & 1u);
    return (unsigned short)(u >> 16);
}
__device__ __forceinline__ float bf2f(unsigned short h) {
    return __uint_as_float(((unsigned int)h) << 16);
}
#define MFMA16(a, b, c) __builtin_amdgcn_mfma_f32_16x16x32_bf16((a), (b), (c), 0, 0, 0)

// ---------------------------------------------------------------------------
// Pack kernels: fp32 [rows][2048] -> bf16 fragment layout. LDS-transposed so
// global reads are fully coalesced float4 and writes are coalesced 16B/lane.
// Block: 256 thr, region [32 rows][128 cols]. MODE 0 = A-pack, 1 = B-pack.
// ---------------------------------------------------------------------------
template<int MODE>
__global__ __launch_bounds__(256) void k_pack(const float* __restrict__ src,
                                              unsigned short* __restrict__ dst)
{
    __shared__ float sA[32][132];
    const int tid = threadIdx.x;
    const int i0 = blockIdx.y * 32;
    const int k0 = blockIdx.x * 128;

    #pragma unroll
    for (int u = 0; u < 4; ++u) {
        const int f = tid + 256 * u;          // 0..1023 float4 slots
        const int row = f >> 5, c4 = (f & 31) << 2;
        *reinterpret_cast<float4*>(&sA[row][c4]) =
            *reinterpret_cast<const float4*>(&src[(size_t)(i0 + row) * DIM + k0 + c4]);
    }
    __syncthreads();

    #pragma unroll
    for (int u = 0; u < 2; ++u) {
        const int s = tid + 256 * u;          // 0..511 lane-slots
        const int lane = s & 63, g = lane >> 4, q = lane & 15;
        ushort8v v;
        size_t idx;
        if (MODE == 0) {
            const int rtl = s >> 8, ktl = (s >> 6) & 3;
            const float* p = &sA[16 * rtl + q][32 * ktl + 8 * g];
            #pragma unroll
            for (int e = 0; e < 8; ++e) v[e] = f2bf(p[e]);
            const size_t rt_g = blockIdx.y * 2 + rtl;
            const size_t kt_g = blockIdx.x * 4 + ktl;
            idx = ((rt_g * 64 + kt_g) * 64 + lane) * 8;
        } else {
            const int kt2l = s >> 6;          // 0..7
            #pragma unroll
            for (int e = 0; e < 8; ++e) v[e] = f2bf(sA[8 * g + e][16 * kt2l + q]);
            const size_t kt2_g = blockIdx.x * 8 + kt2l;
            idx = ((kt2_g * 128 + blockIdx.y) * 64 + lane) * 8;
        }
        *reinterpret_cast<ushort8v*>(&dst[idx]) = v;
    }
}

// ---------------------------------------------------------------------------
// K1: scores = S @ WT^T + bias, fused hinge gradient, writes Gpack (bf16).
// 128 blocks x 128 thr (2 waves). Wave owns 16 rows x 128 classes.
// ---------------------------------------------------------------------------
__global__ __launch_bounds__(128) void k_scores_grad(
    const unsigned short* __restrict__ SpackA,
    const unsigned short* __restrict__ WTpack,
    const float* __restrict__ bias,
    const int* __restrict__ labels,
    unsigned short* __restrict__ Gpack)
{
    const int tid = threadIdx.x;
    const int w = tid >> 6, lane = tid & 63;
    const int g = lane >> 4, q = lane & 15;
    const int rt = blockIdx.x * 2 + w;        // 16-row tile
    const int ibase = rt * 16;

    f32x4 acc[8] = {};
    const unsigned short* ap = SpackA + (size_t)rt * 32768 + lane * 8;
    const unsigned short* bp = WTpack + lane * 8;
    for (int kt = 0; kt < 64; ++kt) {
        const short8v a = *reinterpret_cast<const short8v*>(ap + (size_t)kt * 512);
        const unsigned short* bb = bp + (size_t)kt * 4096;
        #pragma unroll
        for (int jt = 0; jt < 8; ++jt) {
            const short8v b = *reinterpret_cast<const short8v*>(bb + jt * 512);
            acc[jt] = MFMA16(a, b, acc[jt]);
        }
    }

    float bq[8];
    #pragma unroll
    for (int jt = 0; jt < 8; ++jt) bq[jt] = bias[jt * 16 + q];

    const unsigned short BF_GINV = f2bf(GINVF);

    #pragma unroll
    for (int r = 0; r < 4; ++r) {
        const int lr = labels[ibase + 4 * g + r];   // uniform in quarter-wave
        const int jt_l = lr >> 4, q_l = lr & 15;
        float lab_col = 0.0f;                        // this lane's score at col-tile jt_l
        #pragma unroll
        for (int jt = 0; jt < 8; ++jt)
            lab_col = (jt == jt_l) ? (acc[jt][r] + bq[jt]) : lab_col;
        const float scorr = __shfl(lab_col, (lane & 48) | q_l);

        int cnt = 0;
        unsigned short gv[8];
        #pragma unroll
        for (int jt = 0; jt < 8; ++jt) {
            const float s = acc[jt][r] + bq[jt];
            const bool is_lab = (jt == jt_l) && (q == q_l);
            const bool ind = (s - scorr + 1.0f > 0.0f) && !is_lab;
            cnt += ind ? 1 : 0;
            gv[jt] = ind ? BF_GINV : (unsigned short)0;
        }
        cnt += __shfl_xor(cnt, 1); cnt += __shfl_xor(cnt, 2);
        cnt += __shfl_xor(cnt, 4); cnt += __shfl_xor(cnt, 8);

        const int i = ibase + 4 * g + r;
        const int it = i >> 5, g2 = (i & 31) >> 3, e = i & 7;
        #pragma unroll
        for (int jt = 0; jt < 8; ++jt) {
            unsigned short v = gv[jt];
            if (jt == jt_l && q == q_l) v = f2bf(-(float)cnt * GINVF);
            Gpack[((size_t)(jt * 128 + it) * 64 + g2 * 16 + q) * 8 + e] = v;
        }
    }
}

// ---------------------------------------------------------------------------
// K2: dWT = G^T S; WT = WT*SHRINK - LR*dWT; bias -= LR*colsum(G); re-pack W.
// Grid (16 kb, 4 jb) x 128 thr. Wave owns 32 j x 64 k, full i=4096 contraction.
// ---------------------------------------------------------------------------
__global__ __launch_bounds__(128) void k_update(
    const unsigned short* __restrict__ Gpack,
    const unsigned short* __restrict__ SpackB,
    float* __restrict__ WT, float* __restrict__ biasp,
    unsigned short* __restrict__ WTpack)
{
    const int tid = threadIdx.x, w = tid >> 6, lane = tid & 63;
    const int g = lane >> 4, q = lane & 15;
    const int kb = blockIdx.x;                 // 0..15  (128 k each)
    const int jb = blockIdx.y;                 // 0..3   (32 j each)
    const bool do_bias = (kb == 0) && (w == 0);

    f32x4 acc[2][4] = {};
    float bsum0 = 0.0f, bsum1 = 0.0f;

    const unsigned short* ga0 = Gpack + ((size_t)(jb * 2 + 0) * 128 * 64 + lane) * 8;
    const unsigned short* ga1 = Gpack + ((size_t)(jb * 2 + 1) * 128 * 64 + lane) * 8;
    const unsigned short* sb  = SpackB + ((size_t)(kb * 8 + w * 4) * 128 * 64 + lane) * 8;

    for (int it = 0; it < 128; ++it) {
        const short8v a0 = *reinterpret_cast<const short8v*>(ga0 + (size_t)it * 512);
        const short8v a1 = *reinterpret_cast<const short8v*>(ga1 + (size_t)it * 512);
        #pragma unroll
        for (int n = 0; n < 4; ++n) {
            const short8v b = *reinterpret_cast<const short8v*>(
                sb + ((size_t)n * 128 + it) * 512);
            acc[0][n] = MFMA16(a0, b, acc[0][n]);
            acc[1][n] = MFMA16(a1, b, acc[1][n]);
        }
        if (do_bias) {
            #pragma unroll
            for (int e = 0; e < 8; ++e) {
                bsum0 += bf2f((unsigned short)a0[e]);
                bsum1 += bf2f((unsigned short)a1[e]);
            }
        }
    }

    const int j0 = jb * 32, k0 = kb * 128 + w * 64;
    #pragma unroll
    for (int t = 0; t < 2; ++t) {
        #pragma unroll
        for (int n = 0; n < 4; ++n) {
            #pragma unroll
            for (int r = 0; r < 4; ++r) {
                const int j = j0 + 16 * t + 4 * g + r;
                const int k = k0 + 16 * n + q;
                float wv = WT[j * DIM + k];
                wv = wv * SHRINK - LRATE * acc[t][n][r];
                WT[j * DIM + k] = wv;
                const int ktW = k >> 5, jtW = j >> 4, gW = (k & 31) >> 3, eW = k & 7;
                WTpack[((size_t)(ktW * 8 + jtW) * 64 + gW * 16 + (j & 15)) * 8 + eW] = f2bf(wv);
            }
        }
    }

    if (do_bias) {
        float s0 = bsum0, s1 = bsum1;
        s0 += __shfl_xor(s0, 16); s0 += __shfl_xor(s0, 32);
        s1 += __shfl_xor(s1, 16); s1 += __shfl_xor(s1, 32);
        if (g == 0) {
            biasp[j0 + q]      -= LRATE * s0;
            biasp[j0 + 16 + q] -= LRATE * s1;
        }
    }
}

// ---------------------------------------------------------------------------
// K3: out = Q @ WT^T + bias. 256 blocks x 128 thr; wave owns 32 rows x 128 c.
// PACKED=false falls back to reading Q fp32 directly (if ws too small).
// ---------------------------------------------------------------------------
template<bool PACKED>
__global__ __launch_bounds__(128) void k_query(
    const unsigned short* __restrict__ QpackA,
    const float* __restrict__ Qf,
    const unsigned short* __restrict__ WTpack,
    const float* __restrict__ bias,
    float* __restrict__ out)
{
    const int tid = threadIdx.x, w = tid >> 6, lane = tid & 63;
    const int g = lane >> 4, q = lane & 15;
    const int rt0 = blockIdx.x * 4 + w * 2;    // two 16-row tiles

    f32x4 acc[2][8] = {};
    for (int kt = 0; kt < 64; ++kt) {
        short8v a[2];
        #pragma unroll
        for (int t = 0; t < 2; ++t) {
            if (PACKED) {
                a[t] = *reinterpret_cast<const short8v*>(
                    QpackA + ((size_t)(rt0 + t) * 64 + kt) * 512 + lane * 8);
            } else {
                const float* p = Qf + (size_t)((rt0 + t) * 16 + q) * DIM + kt * 32 + 8 * g;
                #pragma unroll
                for (int e = 0; e < 8; ++e) a[t][e] = (short)f2bf(p[e]);
            }
        }
        const unsigned short* bb = WTpack + (size_t)kt * 4096 + lane * 8;
        #pragma unroll
        for (int jt = 0; jt < 8; ++jt) {
            const short8v b = *reinterpret_cast<const short8v*>(bb + jt * 512);
            acc[0][jt] = MFMA16(a[0], b, acc[0][jt]);
            acc[1][jt] = MFMA16(a[1], b, acc[1][jt]);
        }
    }
    #pragma unroll
    for (int t = 0; t < 2; ++t) {
        const int row0 = (rt0 + t) * 16 + 4 * g;
        #pragma unroll
        for (int jt = 0; jt < 8; ++jt) {
            const float bq = bias[jt * 16 + q];
            #pragma unroll
            for (int r = 0; r < 4; ++r)
                out[(size_t)(row0 + r) * NC + jt * 16 + q] = acc[t][jt][r] + bq;
        }
    }
}

// ---------------------------------------------------------------------------
extern "C" void kernel_launch(void* const* d_in, const int* in_sizes, int n_in,
                              void* d_out, int out_size, void* d_ws, size_t ws_size,
                              hipStream_t stream)
{
    const float* S      = (const float*)d_in[0];
    const int*   labels = (const int*)d_in[1];
    const float* Q      = (const float*)d_in[2];
    float* out = (float*)d_out;

    char* ws = (char*)d_ws;
    float*          WT     = (float*)(ws + 0);                 // 1,048,576 B
    float*          bias   = (float*)(ws + 1048576);           // 512 B
    unsigned short* WTpack = (unsigned short*)(ws + 1049088);  // 524,288 B
    unsigned short* Gpack  = (unsigned short*)(ws + 1573376);  // 1,048,576 B
    unsigned short* SpackA = (unsigned short*)(ws + 2621952);  // 16 MB
    unsigned short* SpackB = (unsigned short*)(ws + 19399168); // 16 MB
    unsigned short* QpackA = (unsigned short*)(ws + 36176384); // 64 MB
    const size_t NEED_FULL = 103285248;
    const bool packQ = (ws_size >= NEED_FULL);

    // zero WT + bias + WTpack (contiguous)
    hipMemsetAsync(ws, 0, 1573376, stream);

    k_pack<0><<<dim3(16, 128), 256, 0, stream>>>(S, SpackA);
    k_pack<1><<<dim3(16, 128), 256, 0, stream>>>(S, SpackB);
    if (packQ)
        k_pack<0><<<dim3(16, 512), 256, 0, stream>>>(Q, QpackA);

    for (int it = 0; it < MAX_ITER; ++it) {
        k_scores_grad<<<dim3(128), dim3(128), 0, stream>>>(SpackA, WTpack, bias, labels, Gpack);
        k_update<<<dim3(16, 4), dim3(128), 0, stream>>>(Gpack, SpackB, WT, bias, WTpack);
    }
    if (packQ)
        k_query<true><<<dim3(256), dim3(128), 0, stream>>>(QpackA, Q, WTpack, bias, out);
    else
        k_query<false><<<dim3(256), dim3(128), 0, stream>>>(QpackA, Q, WTpack, bias, out);
}

// Round 3
// 579.560 us; speedup vs baseline: 7.6154x; 3.3574x over previous
//
#include <hip/hip_runtime.h>

// Differentiable SVM (multiclass hinge, 15 GD steps) on MI355X — Round 3.
// bf16 MFMA, fragment-packed operands, parallelism-first per-iter kernels:
//   k_scores_grad: 256 blk x 256 thr (1024 waves), col-split, fused hinge->Gpack
//   k_update:      split-K=8, 1024 blk x 128 thr (2048 waves) -> dWpart
//   k_reduce:      264 blk: 8-way partial sum + W update + re-pack + bias grad
//   k_query:       512 blk x 128 thr (1024 waves)
//
// Fragment layout (v_mfma_f32_16x16x32_bf16), lane l, g=l>>4, q=l&15:
//   A: A[row=q][k=8g+e]  B: B[col=q][k=8g+e]  D: D[row=4g+r][col=q]
// Pack layouts ([tile][lane][8] ushort, 1KB tiles):
//   SpackA/QpackA: tile(rt,kt):  ((rt*64+kt)*64  + 16*((k&31)>>3)+(r&15))*8+(k&7)
//   SpackB:        tile(kt2,it): ((kt2*128+it)*64 + 16*((i&31)>>3)+(k&15))*8+(i&7)
//   WTpack:        tile(kt,jt):  ((kt*8+jt)*64   + 16*((k&31)>>3)+(j&15))*8+(k&7)
//   Gpack:         tile(jt,it):  ((jt*128+it)*64 + 16*((i&31)>>3)+(j&15))*8+(i&7)

#define NS 4096
#define DIM 2048
#define NQ 16384
#define NC 128
#define LRATE 0.01f
#define SHRINK (1.0f - 0.01f * 1.0f)
#define GINVF (1.0f / (4096.0f * 128.0f))   // 2^-19, exact in bf16
#define MAX_ITER 15
#define SK 8

typedef __attribute__((ext_vector_type(8))) short short8v;
typedef __attribute__((ext_vector_type(8))) unsigned short ushort8v;
typedef __attribute__((ext_vector_type(4))) unsigned short ushort4v;
typedef __attribute__((ext_vector_type(4))) float f32x4;

__device__ __forceinline__ unsigned short f2bf(float f) {     // RNE
    unsigned int u = __float_as_uint(f);
    u += 0x7fffu + ((u >> 16) & 1u);
    return (unsigned short)(u >> 16);
}
__device__ __forceinline__ float bf2f(unsigned short h) {
    return __uint_as_float(((unsigned int)h) << 16);
}
#define MFMA16(a, b, c) __builtin_amdgcn_mfma_f32_16x16x32_bf16((a), (b), (c), 0, 0, 0)

// ---------------------------------------------------------------------------
// Pack kernels (unchanged): fp32 [rows][2048] -> bf16 fragment layout.
// ---------------------------------------------------------------------------
template<int MODE>
__global__ __launch_bounds__(256) void k_pack(const float* __restrict__ src,
                                              unsigned short* __restrict__ dst)
{
    __shared__ float sA[32][132];
    const int tid = threadIdx.x;
    const int i0 = blockIdx.y * 32;
    const int k0 = blockIdx.x * 128;

    #pragma unroll
    for (int u = 0; u < 4; ++u) {
        const int f = tid + 256 * u;
        const int row = f >> 5, c4 = (f & 31) << 2;
        *reinterpret_cast<float4*>(&sA[row][c4]) =
            *reinterpret_cast<const float4*>(&src[(size_t)(i0 + row) * DIM + k0 + c4]);
    }
    __syncthreads();

    #pragma unroll
    for (int u = 0; u < 2; ++u) {
        const int s = tid + 256 * u;
        const int lane = s & 63, g = lane >> 4, q = lane & 15;
        ushort8v v;
        size_t idx;
        if (MODE == 0) {
            const int rtl = s >> 8, ktl = (s >> 6) & 3;
            const float* p = &sA[16 * rtl + q][32 * ktl + 8 * g];
            #pragma unroll
            for (int e = 0; e < 8; ++e) v[e] = f2bf(p[e]);
            const size_t rt_g = blockIdx.y * 2 + rtl;
            const size_t kt_g = blockIdx.x * 4 + ktl;
            idx = ((rt_g * 64 + kt_g) * 64 + lane) * 8;
        } else {
            const int kt2l = s >> 6;
            #pragma unroll
            for (int e = 0; e < 8; ++e) v[e] = f2bf(sA[8 * g + e][16 * kt2l + q]);
            const size_t kt2_g = blockIdx.x * 8 + kt2l;
            idx = ((kt2_g * 128 + blockIdx.y) * 64 + lane) * 8;
        }
        *reinterpret_cast<ushort8v*>(&dst[idx]) = v;
    }
}

// ---------------------------------------------------------------------------
// K1: scores + hinge grad -> Gpack. Block = 256 thr (4 waves) owns 16 rows;
// wave w owns class-tiles {2w, 2w+1}. Grid 256 blocks = 1024 waves.
// ---------------------------------------------------------------------------
__global__ __launch_bounds__(256) void k_scores_grad(
    const unsigned short* __restrict__ SpackA,
    const unsigned short* __restrict__ WTpack,
    const float* __restrict__ bias,
    const int* __restrict__ labels,
    unsigned short* __restrict__ Gpack)
{
    __shared__ float sS[16][132];
    __shared__ int   sLab[16];
    __shared__ float sScorr[16];
    __shared__ int   sCnt[16];

    const int tid = threadIdx.x;
    const int w = tid >> 6, lane = tid & 63;
    const int g = lane >> 4, q = lane & 15;
    const int rt = blockIdx.x;                 // 16-row tile, 0..255
    const int ibase = rt * 16;

    if (tid < 16) sLab[tid] = labels[ibase + tid];

    f32x4 acc[2] = {};
    const unsigned short* ap = SpackA + (size_t)rt * 64 * 512 + lane * 8;
    const unsigned short* bp = WTpack + (size_t)(2 * w) * 512 + lane * 8;
    for (int kt = 0; kt < 64; ++kt) {
        const short8v a  = *reinterpret_cast<const short8v*>(ap + (size_t)kt * 512);
        const short8v b0 = *reinterpret_cast<const short8v*>(bp + (size_t)kt * 4096);
        const short8v b1 = *reinterpret_cast<const short8v*>(bp + (size_t)kt * 4096 + 512);
        acc[0] = MFMA16(a, b0, acc[0]);
        acc[1] = MFMA16(a, b1, acc[1]);
    }

    #pragma unroll
    for (int u = 0; u < 2; ++u) {
        const int jt = 2 * w + u;
        const float bq = bias[jt * 16 + q];
        #pragma unroll
        for (int r = 0; r < 4; ++r)
            sS[4 * g + r][jt * 16 + q] = acc[u][r] + bq;
    }
    __syncthreads();

    // Phase A: per-row correct-class score + indicator count
    {
        const int row = tid >> 4;
        const int c0 = (tid & 15) * 8;
        const int lab = sLab[row];
        const float scorr = sS[row][lab];
        int cnt = 0;
        #pragma unroll
        for (int c = 0; c < 8; ++c) {
            const int col = c0 + c;
            cnt += (col != lab && (sS[row][col] - scorr + 1.0f > 0.0f)) ? 1 : 0;
        }
        cnt += __shfl_xor(cnt, 1); cnt += __shfl_xor(cnt, 2);
        cnt += __shfl_xor(cnt, 4); cnt += __shfl_xor(cnt, 8);
        if ((tid & 15) == 0) { sCnt[row] = cnt; sScorr[row] = scorr; }
    }
    __syncthreads();

    // Phase B: write Gpack, one ushort8 (8 rows x 1 class) per thread
    {
        const int j = tid & 127, h = tid >> 7;
        const int jt = j >> 4, qq = j & 15;
        const int it = rt >> 1, g2 = ((rt & 1) << 1) + h;
        const unsigned short BF_GINV = f2bf(GINVF);
        ushort8v gv;
        #pragma unroll
        for (int e = 0; e < 8; ++e) {
            const int row = 8 * h + e;
            const int lab = sLab[row];
            unsigned short v;
            if (j == lab) v = f2bf(-(float)sCnt[row] * GINVF);
            else v = (sS[row][j] - sScorr[row] + 1.0f > 0.0f) ? BF_GINV : (unsigned short)0;
            gv[e] = v;
        }
        *reinterpret_cast<ushort8v*>(
            &Gpack[((size_t)(jt * 128 + it) * 64 + g2 * 16 + qq) * 8]) = gv;
    }
}

// ---------------------------------------------------------------------------
// K2: split-K dW partials. Grid (32 kb, 4 jb, 8 sk) x 128 thr = 2048 waves.
// Wave: acc[2 jt][2 kt2] over 16 it-steps -> dWpart[sk][j][k].
// ---------------------------------------------------------------------------
__global__ __launch_bounds__(128) void k_update(
    const unsigned short* __restrict__ Gpack,
    const unsigned short* __restrict__ SpackB,
    float* __restrict__ dWpart)
{
    const int tid = threadIdx.x, w = tid >> 6, lane = tid & 63;
    const int g = lane >> 4, q = lane & 15;
    const int jt0 = blockIdx.y * 2;
    const int kt2_0 = blockIdx.x * 4 + w * 2;
    const int sk = blockIdx.z;
    const int it0 = sk * 16;

    f32x4 acc[2][2] = {};
    const unsigned short* ga = Gpack  + ((size_t)jt0 * 128 + it0) * 512 + lane * 8;
    const unsigned short* sb = SpackB + ((size_t)kt2_0 * 128 + it0) * 512 + lane * 8;

    for (int it = 0; it < 16; ++it) {
        const short8v a0 = *reinterpret_cast<const short8v*>(ga + (size_t)it * 512);
        const short8v a1 = *reinterpret_cast<const short8v*>(ga + (size_t)it * 512 + 65536);
        const short8v b0 = *reinterpret_cast<const short8v*>(sb + (size_t)it * 512);
        const short8v b1 = *reinterpret_cast<const short8v*>(sb + (size_t)it * 512 + 65536);
        acc[0][0] = MFMA16(a0, b0, acc[0][0]);
        acc[0][1] = MFMA16(a0, b1, acc[0][1]);
        acc[1][0] = MFMA16(a1, b0, acc[1][0]);
        acc[1][1] = MFMA16(a1, b1, acc[1][1]);
    }

    #pragma unroll
    for (int jj = 0; jj < 2; ++jj) {
        #pragma unroll
        for (int n = 0; n < 2; ++n) {
            #pragma unroll
            for (int r = 0; r < 4; ++r) {
                const int j = (jt0 + jj) * 16 + 4 * g + r;
                const int k = (kt2_0 + n) * 16 + q;
                dWpart[((size_t)sk * 128 + j) * 2048 + k] = acc[jj][n][r];
            }
        }
    }
}

// ---------------------------------------------------------------------------
// K3: reduce partials + W update + re-pack; blocks 256..263 do bias grad.
// ---------------------------------------------------------------------------
__global__ __launch_bounds__(256) void k_reduce(
    const float* __restrict__ dWpart,
    const unsigned short* __restrict__ Gpack,
    float* __restrict__ WT, float* __restrict__ biasp,
    unsigned short* __restrict__ WTpack)
{
    __shared__ float sB[16][17];
    const int b = blockIdx.x, t = threadIdx.x;

    if (b < 256) {
        const int j = b >> 1;
        const int kb = (b & 1) * 1024 + t * 4;
        f32x4 s = {};
        #pragma unroll
        for (int sk = 0; sk < SK; ++sk)
            s += *reinterpret_cast<const f32x4*>(
                &dWpart[((size_t)sk * 128 + j) * 2048 + kb]);
        f32x4 wv = *reinterpret_cast<const f32x4*>(&WT[(size_t)j * 2048 + kb]);
        wv = wv * SHRINK - LRATE * s;
        *reinterpret_cast<f32x4*>(&WT[(size_t)j * 2048 + kb]) = wv;

        const int ktW = kb >> 5, gW = (kb & 31) >> 3, jtW = j >> 4;
        ushort4v p;
        p[0] = f2bf(wv[0]); p[1] = f2bf(wv[1]); p[2] = f2bf(wv[2]); p[3] = f2bf(wv[3]);
        *reinterpret_cast<ushort4v*>(
            &WTpack[((size_t)(ktW * 8 + jtW) * 64 + gW * 16 + (j & 15)) * 8 + (kb & 7)]) = p;
    } else {
        const int jt = b - 256;                 // 0..7
        float part = 0.0f;
        #pragma unroll
        for (int u = 0; u < 32; ++u) {
            const int slot = t + 256 * u;       // it*64 + lane; lane = t&63 const
            const ushort8v v = *reinterpret_cast<const ushort8v*>(
                &Gpack[((size_t)jt * 128 * 64 + slot) * 8]);
            #pragma unroll
            for (int e = 0; e < 8; ++e) part += bf2f(v[e]);
        }
        sB[t & 15][t >> 4] = part;
        __syncthreads();
        if (t < 16) {
            float s = 0.0f;
            #pragma unroll
            for (int x = 0; x < 16; ++x) s += sB[t][x];
            biasp[jt * 16 + t] -= LRATE * s;
        }
    }
}

// ---------------------------------------------------------------------------
// K4: out = Q @ WT^T + bias. Wave = 1 row-tile x 8 class-tiles. 1024 waves.
// ---------------------------------------------------------------------------
template<bool PACKED>
__global__ __launch_bounds__(128) void k_query(
    const unsigned short* __restrict__ QpackA,
    const float* __restrict__ Qf,
    const unsigned short* __restrict__ WTpack,
    const float* __restrict__ bias,
    float* __restrict__ out)
{
    const int tid = threadIdx.x, w = tid >> 6, lane = tid & 63;
    const int g = lane >> 4, q = lane & 15;
    const int rt = blockIdx.x * 2 + w;          // 0..1023

    f32x4 acc[8] = {};
    const unsigned short* ap = QpackA + (size_t)rt * 64 * 512 + lane * 8;
    const unsigned short* bp = WTpack + lane * 8;
    for (int kt = 0; kt < 64; ++kt) {
        short8v a;
        if (PACKED) {
            a = *reinterpret_cast<const short8v*>(ap + (size_t)kt * 512);
        } else {
            const float* p = Qf + (size_t)(rt * 16 + q) * DIM + kt * 32 + 8 * g;
            #pragma unroll
            for (int e = 0; e < 8; ++e) a[e] = (short)f2bf(p[e]);
        }
        const unsigned short* bb = bp + (size_t)kt * 4096;
        #pragma unroll
        for (int jt = 0; jt < 8; ++jt) {
            const short8v bv = *reinterpret_cast<const short8v*>(bb + jt * 512);
            acc[jt] = MFMA16(a, bv, acc[jt]);
        }
    }
    const int row0 = rt * 16 + 4 * g;
    #pragma unroll
    for (int jt = 0; jt < 8; ++jt) {
        const float bq = bias[jt * 16 + q];
        #pragma unroll
        for (int r = 0; r < 4; ++r)
            out[(size_t)(row0 + r) * NC + jt * 16 + q] = acc[jt][r] + bq;
    }
}

// ---------------------------------------------------------------------------
extern "C" void kernel_launch(void* const* d_in, const int* in_sizes, int n_in,
                              void* d_out, int out_size, void* d_ws, size_t ws_size,
                              hipStream_t stream)
{
    const float* S      = (const float*)d_in[0];
    const int*   labels = (const int*)d_in[1];
    const float* Q      = (const float*)d_in[2];
    float* out = (float*)d_out;

    char* ws = (char*)d_ws;
    float*          WT     = (float*)(ws + 0);                 // 1,048,576
    float*          bias   = (float*)(ws + 1048576);           // 512
    unsigned short* WTpack = (unsigned short*)(ws + 1049088);  // 524,288
    unsigned short* Gpack  = (unsigned short*)(ws + 1573376);  // 1,048,576
    float*          dWpart = (float*)(ws + 2621952);           // 8,388,608
    unsigned short* SpackA = (unsigned short*)(ws + 11010560); // 16 MB
    unsigned short* SpackB = (unsigned short*)(ws + 27787776); // 16 MB
    unsigned short* QpackA = (unsigned short*)(ws + 44564992); // 64 MB
    const size_t NEED_FULL = 111673856;
    const bool packQ = (ws_size >= NEED_FULL);

    hipMemsetAsync(ws, 0, 1573376, stream);   // WT + bias + WTpack

    k_pack<0><<<dim3(16, 128), 256, 0, stream>>>(S, SpackA);
    k_pack<1><<<dim3(16, 128), 256, 0, stream>>>(S, SpackB);
    if (packQ)
        k_pack<0><<<dim3(16, 512), 256, 0, stream>>>(Q, QpackA);

    for (int it = 0; it < MAX_ITER; ++it) {
        k_scores_grad<<<dim3(256), dim3(256), 0, stream>>>(SpackA, WTpack, bias, labels, Gpack);
        k_update<<<dim3(32, 4, SK), dim3(128), 0, stream>>>(Gpack, SpackB, dWpart);
        k_reduce<<<dim3(264), dim3(256), 0, stream>>>(dWpart, Gpack, WT, bias, WTpack);
    }
    if (packQ)
        k_query<true><<<dim3(512), dim3(128), 0, stream>>>(QpackA, Q, WTpack, bias, out);
    else
        k_query<false><<<dim3(512), dim3(128), 0, stream>>>(QpackA, Q, WTpack, bias, out);
}

// Round 4
// 502.350 us; speedup vs baseline: 8.7859x; 1.1537x over previous
//
#include <hip/hip_runtime.h>

// Differentiable SVM (multiclass hinge, 15 GD steps) on MI355X — Round 4.
// bf16 MFMA, fragment-packed operands. Iteration = 2 kernels:
//   k_scores_grad: 256 blk x 512 thr (2048 waves); A-tile LDS-staged once,
//                  wave = one jt column; fused hinge -> Gpack.
//   k_update:      512 blk x 256 thr (2048 waves); wave = one 16x16 W tile
//                  (it-split x2, LDS pair reduce); fused W update + re-pack
//                  + bias colsum. No split-K partials, no reduce kernel.
//
// Fragment layout (v_mfma_f32_16x16x32_bf16), lane l, g=l>>4, q=l&15:
//   A: A[row=q][k=8g+e]  B: B[col=q][k=8g+e]  D: D[row=4g+r][col=q]
// Pack layouts ([tile][lane][8] ushort, 1KB tiles):
//   SpackA/QpackA: tile(rt,kt):  ((rt*64+kt)*64  + 16*((k&31)>>3)+(r&15))*8+(k&7)
//   SpackB:        tile(kt2,it): ((kt2*128+it)*64 + 16*((i&31)>>3)+(k&15))*8+(i&7)
//   WTpack:        tile(kt,jt):  ((kt*8+jt)*64   + 16*((k&31)>>3)+(j&15))*8+(k&7)
//   Gpack:         tile(jt,it):  ((jt*128+it)*64 + 16*((i&31)>>3)+(j&15))*8+(i&7)

#define NS 4096
#define DIM 2048
#define NQ 16384
#define NC 128
#define LRATE 0.01f
#define SHRINK (1.0f - 0.01f * 1.0f)
#define GINVF (1.0f / (4096.0f * 128.0f))   // 2^-19, exact in bf16
#define MAX_ITER 15

typedef __attribute__((ext_vector_type(8))) short short8v;
typedef __attribute__((ext_vector_type(8))) unsigned short ushort8v;
typedef __attribute__((ext_vector_type(4))) unsigned short ushort4v;
typedef __attribute__((ext_vector_type(4))) float f32x4;

__device__ __forceinline__ unsigned short f2bf(float f) {     // RNE
    unsigned int u = __float_as_uint(f);
    u += 0x7fffu + ((u >> 16) & 1u);
    return (unsigned short)(u >> 16);
}
__device__ __forceinline__ float bf2f(unsigned short h) {
    return __uint_as_float(((unsigned int)h) << 16);
}
#define MFMA16(a, b, c) __builtin_amdgcn_mfma_f32_16x16x32_bf16((a), (b), (c), 0, 0, 0)

// ---------------------------------------------------------------------------
// Pack kernels: fp32 [rows][2048] -> bf16 fragment layout.
// ---------------------------------------------------------------------------
template<int MODE>
__global__ __launch_bounds__(256) void k_pack(const float* __restrict__ src,
                                              unsigned short* __restrict__ dst)
{
    __shared__ float sA[32][132];
    const int tid = threadIdx.x;
    const int i0 = blockIdx.y * 32;
    const int k0 = blockIdx.x * 128;

    #pragma unroll
    for (int u = 0; u < 4; ++u) {
        const int f = tid + 256 * u;
        const int row = f >> 5, c4 = (f & 31) << 2;
        *reinterpret_cast<float4*>(&sA[row][c4]) =
            *reinterpret_cast<const float4*>(&src[(size_t)(i0 + row) * DIM + k0 + c4]);
    }
    __syncthreads();

    #pragma unroll
    for (int u = 0; u < 2; ++u) {
        const int s = tid + 256 * u;
        const int lane = s & 63, g = lane >> 4, q = lane & 15;
        ushort8v v;
        size_t idx;
        if (MODE == 0) {
            const int rtl = s >> 8, ktl = (s >> 6) & 3;
            const float* p = &sA[16 * rtl + q][32 * ktl + 8 * g];
            #pragma unroll
            for (int e = 0; e < 8; ++e) v[e] = f2bf(p[e]);
            const size_t rt_g = blockIdx.y * 2 + rtl;
            const size_t kt_g = blockIdx.x * 4 + ktl;
            idx = ((rt_g * 64 + kt_g) * 64 + lane) * 8;
        } else {
            const int kt2l = s >> 6;
            #pragma unroll
            for (int e = 0; e < 8; ++e) v[e] = f2bf(sA[8 * g + e][16 * kt2l + q]);
            const size_t kt2_g = blockIdx.x * 8 + kt2l;
            idx = ((kt2_g * 128 + blockIdx.y) * 64 + lane) * 8;
        }
        *reinterpret_cast<ushort8v*>(&dst[idx]) = v;
    }
}

// ---------------------------------------------------------------------------
// K1: scores + hinge grad -> Gpack. 256 blocks x 512 thr (8 waves).
// Block owns rt (16 rows); A-tile (64 KB) staged to LDS once; wave w = jt.
// ---------------------------------------------------------------------------
__global__ __launch_bounds__(512) void k_scores_grad(
    const unsigned short* __restrict__ SpackA,
    const unsigned short* __restrict__ WTpack,
    const float* __restrict__ bias,
    const int* __restrict__ labels,
    unsigned short* __restrict__ Gpack)
{
    __shared__ unsigned short sQ[32768];   // 64 KB A-tile, fragment order
    __shared__ float sS[16][132];
    __shared__ int   sLab[16];
    __shared__ float sScorr[16];
    __shared__ int   sCnt[16];

    const int tid = threadIdx.x;
    const int w = tid >> 6, lane = tid & 63;
    const int g = lane >> 4, q = lane & 15;
    const int rt = blockIdx.x;
    const int ibase = rt * 16;

    if (tid < 16) sLab[tid] = labels[ibase + tid];

    {   // stage A tile: linear 64 KB copy, 16B x 8 per thread
        const unsigned short* src = SpackA + (size_t)rt * 32768;
        #pragma unroll
        for (int u = 0; u < 8; ++u) {
            const int o = (tid + 512 * u) * 8;
            *reinterpret_cast<ushort8v*>(&sQ[o]) =
                *reinterpret_cast<const ushort8v*>(&src[o]);
        }
    }
    __syncthreads();

    const int jt = w;
    f32x4 acc = {};
    const unsigned short* bp = WTpack + (size_t)jt * 512 + lane * 8;
    #pragma unroll 4
    for (int kt = 0; kt < 64; ++kt) {
        const short8v a = *reinterpret_cast<const short8v*>(&sQ[(kt * 64 + lane) * 8]);
        const short8v b = *reinterpret_cast<const short8v*>(bp + (size_t)kt * 4096);
        acc = MFMA16(a, b, acc);
    }

    const float bq = bias[jt * 16 + q];
    #pragma unroll
    for (int r = 0; r < 4; ++r)
        sS[4 * g + r][jt * 16 + q] = acc[r] + bq;
    __syncthreads();

    // Phase A: per-row correct-class score + indicator count (256 thr)
    if (tid < 256) {
        const int row = tid >> 4;
        const int c0 = (tid & 15) * 8;
        const int lab = sLab[row];
        const float scorr = sS[row][lab];
        int cnt = 0;
        #pragma unroll
        for (int c = 0; c < 8; ++c) {
            const int col = c0 + c;
            cnt += (col != lab && (sS[row][col] - scorr + 1.0f > 0.0f)) ? 1 : 0;
        }
        cnt += __shfl_xor(cnt, 1); cnt += __shfl_xor(cnt, 2);
        cnt += __shfl_xor(cnt, 4); cnt += __shfl_xor(cnt, 8);
        if ((tid & 15) == 0) { sCnt[row] = cnt; sScorr[row] = scorr; }
    }
    __syncthreads();

    // Phase B: write Gpack, one ushort8 (8 rows x 1 class) per thread (256 thr)
    if (tid < 256) {
        const int j = tid & 127, h = tid >> 7;
        const int jt2 = j >> 4, qq = j & 15;
        const int it = rt >> 1, g2 = ((rt & 1) << 1) + h;
        const unsigned short BF_GINV = f2bf(GINVF);
        ushort8v gv;
        #pragma unroll
        for (int e = 0; e < 8; ++e) {
            const int row = 8 * h + e;
            const int lab = sLab[row];
            unsigned short v;
            if (j == lab) v = f2bf(-(float)sCnt[row] * GINVF);
            else v = (sS[row][j] - sScorr[row] + 1.0f > 0.0f) ? BF_GINV : (unsigned short)0;
            gv[e] = v;
        }
        *reinterpret_cast<ushort8v*>(
            &Gpack[((size_t)(jt2 * 128 + it) * 64 + g2 * 16 + qq) * 8]) = gv;
    }
}

// ---------------------------------------------------------------------------
// K2: fused dW GEMM + W update + re-pack + bias grad.
// Grid 512 blk x 256 thr (4 waves) = 2048 waves. Wave = tile (jt,kt2), it-half h.
// ---------------------------------------------------------------------------
__global__ __launch_bounds__(256) void k_update(
    const unsigned short* __restrict__ Gpack,
    const unsigned short* __restrict__ SpackB,
    float* __restrict__ WT, float* __restrict__ biasp,
    unsigned short* __restrict__ WTpack)
{
    __shared__ f32x4 sRed[2][64];
    __shared__ float sBias[2][16];

    const int tid = threadIdx.x, w = tid >> 6, lane = tid & 63;
    const int g = lane >> 4, q = lane & 15;
    const int tl = w >> 1, h = w & 1;
    const int task = blockIdx.x * 2 + tl;
    const int jt = task >> 7, kt2 = task & 127;
    const int it0 = h * 64;
    const bool bias_tile = (kt2 == 0);

    f32x4 acc = {};
    float bsum = 0.0f;
    const unsigned short* ga = Gpack  + ((size_t)jt * 128 + it0) * 512 + lane * 8;
    const unsigned short* sb = SpackB + ((size_t)kt2 * 128 + it0) * 512 + lane * 8;

    if (bias_tile) {
        #pragma unroll 4
        for (int it = 0; it < 64; ++it) {
            const short8v a = *reinterpret_cast<const short8v*>(ga + (size_t)it * 512);
            const short8v b = *reinterpret_cast<const short8v*>(sb + (size_t)it * 512);
            acc = MFMA16(a, b, acc);
            #pragma unroll
            for (int e = 0; e < 8; ++e) bsum += bf2f((unsigned short)a[e]);
        }
    } else {
        #pragma unroll 4
        for (int it = 0; it < 64; ++it) {
            const short8v a = *reinterpret_cast<const short8v*>(ga + (size_t)it * 512);
            const short8v b = *reinterpret_cast<const short8v*>(sb + (size_t)it * 512);
            acc = MFMA16(a, b, acc);
        }
    }

    if (h == 1) sRed[tl][lane] = acc;
    __syncthreads();
    if (h == 0) {
        acc += sRed[tl][lane];
        #pragma unroll
        for (int r = 0; r < 4; ++r) {
            const int j = jt * 16 + 4 * g + r;
            const int k = kt2 * 16 + q;
            float wv = WT[(size_t)j * DIM + k];
            wv = wv * SHRINK - LRATE * acc[r];
            WT[(size_t)j * DIM + k] = wv;
            WTpack[((size_t)((k >> 5) * 8 + (j >> 4)) * 64
                    + ((k & 31) >> 3) * 16 + (j & 15)) * 8 + (k & 7)] = f2bf(wv);
        }
    }

    if (bias_tile) {
        bsum += __shfl_xor(bsum, 16);
        bsum += __shfl_xor(bsum, 32);
        if (lane < 16) sBias[h][lane] = bsum;
    }
    __syncthreads();
    if (bias_tile && w == 0 && lane < 16)
        biasp[jt * 16 + lane] -= LRATE * (sBias[0][lane] + sBias[1][lane]);
}

// ---------------------------------------------------------------------------
// K3: out = Q @ WT^T + bias. Wave = 1 row-tile x 8 class-tiles. 1024 waves.
// ---------------------------------------------------------------------------
template<bool PACKED>
__global__ __launch_bounds__(128) void k_query(
    const unsigned short* __restrict__ QpackA,
    const float* __restrict__ Qf,
    const unsigned short* __restrict__ WTpack,
    const float* __restrict__ bias,
    float* __restrict__ out)
{
    const int tid = threadIdx.x, w = tid >> 6, lane = tid & 63;
    const int g = lane >> 4, q = lane & 15;
    const int rt = blockIdx.x * 2 + w;

    f32x4 acc[8] = {};
    const unsigned short* ap = QpackA + (size_t)rt * 64 * 512 + lane * 8;
    const unsigned short* bp = WTpack + lane * 8;
    for (int kt = 0; kt < 64; ++kt) {
        short8v a;
        if (PACKED) {
            a = *reinterpret_cast<const short8v*>(ap + (size_t)kt * 512);
        } else {
            const float* p = Qf + (size_t)(rt * 16 + q) * DIM + kt * 32 + 8 * g;
            #pragma unroll
            for (int e = 0; e < 8; ++e) a[e] = (short)f2bf(p[e]);
        }
        const unsigned short* bb = bp + (size_t)kt * 4096;
        #pragma unroll
        for (int jt = 0; jt < 8; ++jt) {
            const short8v bv = *reinterpret_cast<const short8v*>(bb + jt * 512);
            acc[jt] = MFMA16(a, bv, acc[jt]);
        }
    }
    const int row0 = rt * 16 + 4 * g;
    #pragma unroll
    for (int jt = 0; jt < 8; ++jt) {
        const float bq = bias[jt * 16 + q];
        #pragma unroll
        for (int r = 0; r < 4; ++r)
            out[(size_t)(row0 + r) * NC + jt * 16 + q] = acc[jt][r] + bq;
    }
}

// ---------------------------------------------------------------------------
extern "C" void kernel_launch(void* const* d_in, const int* in_sizes, int n_in,
                              void* d_out, int out_size, void* d_ws, size_t ws_size,
                              hipStream_t stream)
{
    const float* S      = (const float*)d_in[0];
    const int*   labels = (const int*)d_in[1];
    const float* Q      = (const float*)d_in[2];
    float* out = (float*)d_out;

    char* ws = (char*)d_ws;
    float*          WT     = (float*)(ws + 0);                 // 1,048,576
    float*          bias   = (float*)(ws + 1048576);           // 512
    unsigned short* WTpack = (unsigned short*)(ws + 1049088);  // 524,288
    unsigned short* Gpack  = (unsigned short*)(ws + 1573376);  // 1,048,576
    unsigned short* SpackA = (unsigned short*)(ws + 2621952);  // 16 MB
    unsigned short* SpackB = (unsigned short*)(ws + 19399168); // 16 MB
    unsigned short* QpackA = (unsigned short*)(ws + 36176384); // 64 MB
    const size_t NEED_FULL = 103285248;
    const bool packQ = (ws_size >= NEED_FULL);

    hipMemsetAsync(ws, 0, 1573376, stream);   // WT + bias + WTpack

    k_pack<0><<<dim3(16, 128), 256, 0, stream>>>(S, SpackA);
    k_pack<1><<<dim3(16, 128), 256, 0, stream>>>(S, SpackB);
    if (packQ)
        k_pack<0><<<dim3(16, 512), 256, 0, stream>>>(Q, QpackA);

    for (int it = 0; it < MAX_ITER; ++it) {
        k_scores_grad<<<dim3(256), dim3(512), 0, stream>>>(SpackA, WTpack, bias, labels, Gpack);
        k_update<<<dim3(512), dim3(256), 0, stream>>>(Gpack, SpackB, WT, bias, WTpack);
    }
    if (packQ)
        k_query<true><<<dim3(512), dim3(128), 0, stream>>>(QpackA, Q, WTpack, bias, out);
    else
        k_query<false><<<dim3(512), dim3(128), 0, stream>>>(QpackA, Q, WTpack, bias, out);
}